// Round 5
// baseline (500.657 us; speedup 1.0000x reference)
//
#include <hip/hip_runtime.h>
#include <hip/hip_bf16.h>
#include <math.h>

#define NB 4096      // tokens
#define ND 1024      // model dim
#define NH 4096      // hidden dim
#define NE 8         // experts
#define NKK 2        // top-k
#define NROWS (NB*NKK)   // 8192 (token,slot) rows
#define MAXT 72          // max 128-row tiles (64 full + up to 7 partial)

typedef __attribute__((ext_vector_type(8))) short short8;
typedef __attribute__((ext_vector_type(4))) float f32x4;

__device__ __forceinline__ void gload_lds16(const void* g, void* l) {
    __builtin_amdgcn_global_load_lds(
        (const __attribute__((address_space(1))) unsigned int*)g,
        (__attribute__((address_space(3))) unsigned int*)l, 16, 0, 0);
}

__device__ __forceinline__ unsigned short f2bf(float f) {
    __hip_bfloat16 h = __float2bfloat16(f);
    return *reinterpret_cast<unsigned short*>(&h);
}

// exact-gelu via A&S 7.1.26 erf approx (|erf err| < 1.5e-7), hw exp/rcp
__device__ __forceinline__ float fast_gelu(float x) {
    float xs  = x * 0.70710678118654752f;
    float axs = fabsf(xs);
    float t   = __builtin_amdgcn_rcpf(1.0f + 0.3275911f * axs);
    float p   = t * (0.254829592f + t * (-0.284496736f + t * (1.421413741f +
                t * (-1.453152027f + t * 1.061405429f))));
    float e   = __expf(-xs * xs);
    float erf_abs = 1.0f - p * e;
    float erf = copysignf(erf_abs, x);
    return 0.5f * x * (1.0f + erf);
}

// ---------------- prep kernels ----------------

// in: [E][R][C] f32  ->  out: [E][C][R] bf16  (transpose + convert)
__global__ void k_transpose_cvt(const float* __restrict__ in, __hip_bfloat16* __restrict__ out,
                                int R, int C) {
    __shared__ float tile[64][68];
    const size_t ebase = (size_t)blockIdx.z * R * C;
    const int r0 = blockIdx.y * 64, c0 = blockIdx.x * 64;
    const int t = threadIdx.x;
    const int lr = t >> 4, lc4 = (t & 15) * 4;
    #pragma unroll
    for (int i = 0; i < 4; ++i) {
        int r = lr + i * 16;
        float4 v = *reinterpret_cast<const float4*>(&in[ebase + (size_t)(r0 + r) * C + (c0 + lc4)]);
        *reinterpret_cast<float4*>(&tile[r][lc4]) = v;
    }
    __syncthreads();
    const int q = t & 15, cw = t >> 4;
    #pragma unroll
    for (int i = 0; i < 4; ++i) {
        int cc = cw + i * 16;
        ushort4 v;
        v.x = f2bf(tile[q*4+0][cc]);
        v.y = f2bf(tile[q*4+1][cc]);
        v.z = f2bf(tile[q*4+2][cc]);
        v.w = f2bf(tile[q*4+3][cc]);
        *reinterpret_cast<ushort4*>(&out[ebase + (size_t)(c0 + cc) * R + (r0 + q*4)]) = v;
    }
}

// ---------------- routing ----------------

__global__ void k_route_count(const int* __restrict__ idx, int* cnt) {
    int b = blockIdx.x * 256 + threadIdx.x;
    if (b < NB) {
        atomicAdd(&cnt[idx[2*b]], 1);
        atomicAdd(&cnt[idx[2*b+1]], 1);
    }
}

// prefix offsets + expert-pure 128-row tile list
__global__ void k_route_scan(const int* __restrict__ cnt, int* offs, int* cursor,
                             int* tile_e, int* tile_row, int* ntiles) {
    if (threadIdx.x == 0) {
        int s = 0, t = 0;
        for (int e = 0; e < NE; ++e) {
            offs[e] = s; cursor[e] = s;
            for (int r = 0; r < cnt[e]; r += 128) {
                tile_e[t] = e; tile_row[t] = s + r; ++t;
            }
            s += cnt[e];
        }
        offs[NE] = s;
        *ntiles = t;
    }
}

__global__ void k_route_fill(const int* __restrict__ idx, const float* __restrict__ hw,
                             int* cursor, int* tok, float* gw) {
    int b = blockIdx.x * 256 + threadIdx.x;
    if (b < NB) {
        #pragma unroll
        for (int k = 0; k < NKK; ++k) {
            int e = idx[2*b + k];
            int p = atomicAdd(&cursor[e], 1);
            tok[p] = b;
            gw[p]  = hw[2*b + k];
        }
    }
}

// gather + f32->bf16: Ag[row] = bf16(x[tok[row]])   (one block per row)
__global__ void k_gather_cvt(const float* __restrict__ x, const int* __restrict__ tok,
                             __hip_bfloat16* __restrict__ Ag) {
    const int row = blockIdx.x;
    const float4 v = reinterpret_cast<const float4*>(x + (size_t)tok[row] * ND)[threadIdx.x];
    ushort4 u; u.x = f2bf(v.x); u.y = f2bf(v.y); u.z = f2bf(v.z); u.w = f2bf(v.w);
    reinterpret_cast<ushort4*>(Ag + (size_t)row * ND)[threadIdx.x] = u;
}

// ---- grouped GEMM: BM=128, BK=64, counted-vmcnt double-buffered pipeline ----
// STAGE 1: h = gelu(Ag @ w1t^T + b1)    BN=256, 512 thr (8 waves 2x4), KT=16
// STAGE 2: out += gw*(h @ w2t^T + b2)   BN=128, 256 thr (4 waves 2x2), KT=32, splitK=2
//
// Pipeline invariants (race analysis):
//  - compute(t) reads buf[t&1]; barrier B1 after => all waves done reading.
//  - stage(t+2) then overwrites buf[t&1] (safe after B1).
//  - vmcnt(LOADS_PER_TILE) leaves only t+2's own ops outstanding => t+1's
//    staging complete for THIS wave; barrier B2 => complete for ALL waves.
//  - next iteration reads buf[(t+1)&1]: data ready. vmcnt never 0 mid-loop.

template<int STAGE>
__global__ __launch_bounds__((STAGE == 1) ? 512 : 256, 2) void moe_gemm(
    const __hip_bfloat16* __restrict__ Asrc,   // Ag (st1) or h (st2), contiguous rows
    const __hip_bfloat16* __restrict__ Bt,     // [E][N][K] bf16
    const float* __restrict__ bias,            // [E][N]
    __hip_bfloat16* __restrict__ Hout,
    float* __restrict__ Out,
    const int* __restrict__ offs,
    const int* __restrict__ tok,
    const float* __restrict__ gw,
    const int* __restrict__ tile_e,
    const int* __restrict__ tile_row,
    const int* __restrict__ ntiles)
{
    constexpr int N    = (STAGE == 1) ? NH : ND;
    constexpr int KROW = (STAGE == 1) ? ND : NH;    // row stride of Asrc & Bt
    constexpr int KT   = (STAGE == 1) ? 16 : 32;    // K-tiles of 64
    constexpr int BN   = (STAGE == 1) ? 256 : 128;
    constexpr int THREADS = (STAGE == 1) ? 512 : 256;
    constexpr int ALr  = (128 * 64) / (THREADS * 8);  // A load rounds: 2 / 4
    constexpr int BLr  = (BN * 64) / (THREADS * 8);   // B load rounds: 4 / 4
    constexpr int ATS  = 128 * 64;                    // A tile elements
    constexpr int BUF  = ATS + BN * 64;

    extern __shared__ __hip_bfloat16 smem[];          // 2 * BUF

    // 2D XCD partition: tile-group (xcd>>1) x {N-half (st1) | K-half (st2)}
    const int bid = blockIdx.x;
    const int xcd = bid & 7;
    const int c   = bid >> 3;              // 0..143
    const int tile = (xcd >> 1) * 18 + (c % 18);
    const int sub  = c / 18;               // 0..7
    if (tile >= *ntiles) return;

    int nt, kbase;
    if (STAGE == 1) { nt = (xcd & 1) * 8 + sub; kbase = 0; }
    else            { nt = sub;                 kbase = (xcd & 1) * (NH / 2); }

    const int e = tile_e[tile];
    const int rowbase = tile_row[tile];
    const int end = offs[e + 1];

    const int tid = threadIdx.x;
    const int w = tid >> 6, l = tid & 63;
    const int srow = tid >> 3;
    const int schunk = (tid & 7) ^ (srow & 7);   // source-side XOR swizzle

    const __hip_bfloat16* aptr[ALr];
    #pragma unroll
    for (int r = 0; r < ALr; ++r) {
        int re = rowbase + srow + r * (THREADS / 8);
        if (re > end - 1) re = end - 1;
        aptr[r] = Asrc + (size_t)re * KROW + kbase + schunk * 8;
    }
    const __hip_bfloat16* bptr[BLr];
    #pragma unroll
    for (int r = 0; r < BLr; ++r)
        bptr[r] = Bt + ((size_t)e * N + (size_t)(nt * BN + srow + r * (THREADS / 8))) * KROW
                  + kbase + schunk * 8;

    const int wm = (STAGE == 1) ? (w >> 2) : (w >> 1);   // 2 M-waves
    const int wn = (STAGE == 1) ? (w & 3)  : (w & 1);    // 4 / 2 N-waves
    const int l15 = l & 15, l4 = l >> 4;

    // swizzled ds_read byte offsets: row&7 == l15&7 for all frag rows
    const int cs[2] = { ((l4) ^ (l15 & 7)) * 16, ((4 + l4) ^ (l15 & 7)) * 16 };
    const int abase = (wm * 64 + l15) * 128;
    const int bbase = (wn * 64 + l15) * 128;

    f32x4 acc[4][4];
    #pragma unroll
    for (int mi = 0; mi < 4; ++mi)
        #pragma unroll
        for (int ni = 0; ni < 4; ++ni) acc[mi][ni] = (f32x4){0.f, 0.f, 0.f, 0.f};

    auto stage_t = [&](int b, int kt) {
        __hip_bfloat16* da = smem + b * BUF;
        __hip_bfloat16* db = da + ATS;
        #pragma unroll
        for (int r = 0; r < ALr; ++r)
            gload_lds16(aptr[r] + kt * 64, da + tid * 8 + r * THREADS * 8);
        #pragma unroll
        for (int r = 0; r < BLr; ++r)
            gload_lds16(bptr[r] + kt * 64, db + tid * 8 + r * THREADS * 8);
    };

    // wait until only the newest LOADS_PER_TILE (=ALr+BLr) ops are outstanding
    #define WAIT_VM_TILE() do { \
        if constexpr (STAGE == 1) asm volatile("s_waitcnt vmcnt(6)" ::: "memory"); \
        else                      asm volatile("s_waitcnt vmcnt(8)" ::: "memory"); } while (0)

    stage_t(0, 0);
    stage_t(1, 1);
    WAIT_VM_TILE();                         // tile 0 fully resident
    __builtin_amdgcn_s_barrier();
    __builtin_amdgcn_sched_barrier(0);

    #pragma unroll 1
    for (int kt = 0; kt < KT; ++kt) {
        const int cur = kt & 1;
        const char* sa = (const char*)(smem + cur * BUF);
        const char* sb = (const char*)(smem + cur * BUF + ATS);
        short8 af[4][2], bfv[4][2];
        #pragma unroll
        for (int mi = 0; mi < 4; ++mi)
            #pragma unroll
            for (int ks = 0; ks < 2; ++ks)
                af[mi][ks] = *(const short8*)(sa + abase + mi * 2048 + cs[ks]);
        #pragma unroll
        for (int ni = 0; ni < 4; ++ni)
            #pragma unroll
            for (int ks = 0; ks < 2; ++ks)
                bfv[ni][ks] = *(const short8*)(sb + bbase + ni * 2048 + cs[ks]);
        #pragma unroll
        for (int mi = 0; mi < 4; ++mi)
            #pragma unroll
            for (int ni = 0; ni < 4; ++ni)
                #pragma unroll
                for (int ks = 0; ks < 2; ++ks)
                    acc[mi][ni] = __builtin_amdgcn_mfma_f32_16x16x32_bf16(
                        af[mi][ks], bfv[ni][ks], acc[mi][ni], 0, 0, 0);

        __builtin_amdgcn_s_barrier();       // B1: all waves done reading buf[cur]
        __builtin_amdgcn_sched_barrier(0);
        if (kt + 2 < KT) stage_t(cur, kt + 2);
        if (kt + 1 < KT) {
            if (kt + 2 < KT) WAIT_VM_TILE();
            else             asm volatile("s_waitcnt vmcnt(0)" ::: "memory");
            __builtin_amdgcn_s_barrier();   // B2: tile kt+1 resident for all waves
            __builtin_amdgcn_sched_barrier(0);
        }
    }
    #undef WAIT_VM_TILE

    // epilogue --- C/D frag layout: col = l&15, row = (l>>4)*4 + j  [m89]
    const int ncol0 = nt * BN + wn * 64;
    #pragma unroll
    for (int mi = 0; mi < 4; ++mi) {
        #pragma unroll
        for (int ni = 0; ni < 4; ++ni) {
            const int gn = ncol0 + ni * 16 + l15;
            const float bv = bias[e * N + gn];
            #pragma unroll
            for (int j = 0; j < 4; ++j) {
                const int re = rowbase + wm * 64 + mi * 16 + l4 * 4 + j;
                if (re < end) {
                    float v = acc[mi][ni][j];
                    if (STAGE == 1) {
                        v += bv;
                        Hout[(size_t)re * NH + gn] = __float2bfloat16(fast_gelu(v));
                    } else {
                        if (kbase == 0) v += bv;
                        atomicAdd(&Out[(size_t)tok[re] * ND + gn], gw[re] * v);
                    }
                }
            }
        }
    }
}

// ---------------- launch ----------------

extern "C" void kernel_launch(void* const* d_in, const int* in_sizes, int n_in,
                              void* d_out, int out_size, void* d_ws, size_t ws_size,
                              hipStream_t stream) {
    const float* x   = (const float*)d_in[0];
    const int*   idx = (const int*)d_in[1];
    const float* hw  = (const float*)d_in[2];
    const float* w1  = (const float*)d_in[3];
    const float* b1  = (const float*)d_in[4];
    const float* w2  = (const float*)d_in[5];
    const float* b2  = (const float*)d_in[6];
    float* out = (float*)d_out;

    char* ws = (char*)d_ws;
    size_t off = 0;
    __hip_bfloat16* Ag  = (__hip_bfloat16*)(ws + off); off += (size_t)NROWS * ND * 2;
    __hip_bfloat16* w1t = (__hip_bfloat16*)(ws + off); off += (size_t)NE * ND * NH * 2;
    __hip_bfloat16* w2t = (__hip_bfloat16*)(ws + off); off += (size_t)NE * NH * ND * 2;
    __hip_bfloat16* h   = (__hip_bfloat16*)(ws + off); off += (size_t)NROWS * NH * 2;
    int*   tok     = (int*)(ws + off);   off += NROWS * 4;
    float* gwb     = (float*)(ws + off); off += NROWS * 4;
    int*   cnt     = (int*)(ws + off);   off += 16 * 4;
    int*   offs    = (int*)(ws + off);   off += 16 * 4;
    int*   cursor  = (int*)(ws + off);   off += 16 * 4;
    int*   tile_e  = (int*)(ws + off);   off += MAXT * 4;
    int*   tile_row= (int*)(ws + off);   off += MAXT * 4;
    int*   ntiles  = (int*)(ws + off);   off += 16 * 4;
    (void)ws_size; (void)in_sizes; (void)n_in; (void)out_size;

    hipFuncSetAttribute((const void*)moe_gemm<1>,
                        hipFuncAttributeMaxDynamicSharedMemorySize, 98304);
    hipFuncSetAttribute((const void*)moe_gemm<2>,
                        hipFuncAttributeMaxDynamicSharedMemorySize, 65536);

    hipMemsetAsync(d_out, 0, (size_t)NB * ND * sizeof(float), stream);
    hipMemsetAsync(cnt, 0, 16 * 4, stream);

    k_route_count<<<dim3((NB + 255) / 256), 256, 0, stream>>>(idx, cnt);
    k_route_scan<<<1, 64, 0, stream>>>(cnt, offs, cursor, tile_e, tile_row, ntiles);
    k_route_fill<<<dim3((NB + 255) / 256), 256, 0, stream>>>(idx, hw, cursor, tok, gwb);
    k_gather_cvt<<<dim3(NROWS), 256, 0, stream>>>(x, tok, Ag);
    k_transpose_cvt<<<dim3(NH / 64, ND / 64, NE), 256, 0, stream>>>(w1, w1t, ND, NH);
    k_transpose_cvt<<<dim3(ND / 64, NH / 64, NE), 256, 0, stream>>>(w2, w2t, NH, ND);

    moe_gemm<1><<<dim3(8 * 144), 512, 98304, stream>>>(
        Ag, w1t, b1, h, nullptr, offs, tok, gwb, tile_e, tile_row, ntiles);
    moe_gemm<2><<<dim3(8 * 144), 256, 65536, stream>>>(
        h, w2t, b2, nullptr, out, offs, tok, gwb, tile_e, tile_row, ntiles);
}

// Round 6
// 427.630 us; speedup vs baseline: 1.1708x; 1.1708x over previous
//
#include <hip/hip_runtime.h>
#include <hip/hip_bf16.h>
#include <math.h>

#define NB 4096      // tokens
#define ND 1024      // model dim
#define NH 4096      // hidden dim
#define NE 8         // experts
#define NKK 2        // top-k
#define NROWS (NB*NKK)   // 8192 (token,slot) rows
#define MAXT 72          // max 128-row tiles (64 full + up to 8 partial)

typedef __attribute__((ext_vector_type(8))) short short8;
typedef __attribute__((ext_vector_type(4))) float f32x4;

__device__ __forceinline__ void gload_lds16(const void* g, void* l) {
    __builtin_amdgcn_global_load_lds(
        (const __attribute__((address_space(1))) unsigned int*)g,
        (__attribute__((address_space(3))) unsigned int*)l, 16, 0, 0);
}

__device__ __forceinline__ unsigned short f2bf(float f) {
    __hip_bfloat16 h = __float2bfloat16(f);
    return *reinterpret_cast<unsigned short*>(&h);
}

// exact-gelu via A&S 7.1.26 erf approx (|erf err| < 1.5e-7), hw exp/rcp
__device__ __forceinline__ float fast_gelu(float x) {
    float xs  = x * 0.70710678118654752f;
    float axs = fabsf(xs);
    float t   = __builtin_amdgcn_rcpf(1.0f + 0.3275911f * axs);
    float p   = t * (0.254829592f + t * (-0.284496736f + t * (1.421413741f +
                t * (-1.453152027f + t * 1.061405429f))));
    float e   = __expf(-xs * xs);
    float erf_abs = 1.0f - p * e;
    float erf = copysignf(erf_abs, x);
    return 0.5f * x * (1.0f + erf);
}

// ---------------- prep kernels ----------------

// in: [E][R][C] f32  ->  out: [E][C][R] bf16  (transpose + convert)
__global__ void k_transpose_cvt(const float* __restrict__ in, __hip_bfloat16* __restrict__ out,
                                int R, int C) {
    __shared__ float tile[64][68];
    const size_t ebase = (size_t)blockIdx.z * R * C;
    const int r0 = blockIdx.y * 64, c0 = blockIdx.x * 64;
    const int t = threadIdx.x;
    const int lr = t >> 4, lc4 = (t & 15) * 4;
    #pragma unroll
    for (int i = 0; i < 4; ++i) {
        int r = lr + i * 16;
        float4 v = *reinterpret_cast<const float4*>(&in[ebase + (size_t)(r0 + r) * C + (c0 + lc4)]);
        *reinterpret_cast<float4*>(&tile[r][lc4]) = v;
    }
    __syncthreads();
    const int q = t & 15, cw = t >> 4;
    #pragma unroll
    for (int i = 0; i < 4; ++i) {
        int cc = cw + i * 16;
        ushort4 v;
        v.x = f2bf(tile[q*4+0][cc]);
        v.y = f2bf(tile[q*4+1][cc]);
        v.z = f2bf(tile[q*4+2][cc]);
        v.w = f2bf(tile[q*4+3][cc]);
        *reinterpret_cast<ushort4*>(&out[ebase + (size_t)(c0 + cc) * R + (r0 + q*4)]) = v;
    }
}

// ---------------- routing ----------------

__global__ void k_route_count(const int* __restrict__ idx, int* cnt) {
    int b = blockIdx.x * 256 + threadIdx.x;
    if (b < NB) {
        atomicAdd(&cnt[idx[2*b]], 1);
        atomicAdd(&cnt[idx[2*b+1]], 1);
    }
}

// prefix offsets + expert-pure 128-row tile list
__global__ void k_route_scan(const int* __restrict__ cnt, int* offs, int* cursor,
                             int* tile_e, int* tile_row, int* ntiles) {
    if (threadIdx.x == 0) {
        int s = 0, t = 0;
        for (int e = 0; e < NE; ++e) {
            offs[e] = s; cursor[e] = s;
            for (int r = 0; r < cnt[e]; r += 128) {
                tile_e[t] = e; tile_row[t] = s + r; ++t;
            }
            s += cnt[e];
        }
        offs[NE] = s;
        *ntiles = t;
    }
}

__global__ void k_route_fill(const int* __restrict__ idx, const float* __restrict__ hw,
                             int* cursor, int* tok, float* gw) {
    int b = blockIdx.x * 256 + threadIdx.x;
    if (b < NB) {
        #pragma unroll
        for (int k = 0; k < NKK; ++k) {
            int e = idx[2*b + k];
            int p = atomicAdd(&cursor[e], 1);
            tok[p] = b;
            gw[p]  = hw[2*b + k];
        }
    }
}

// gather + f32->bf16: Ag[row] = bf16(x[tok[row]])   (one block per row)
__global__ void k_gather_cvt(const float* __restrict__ x, const int* __restrict__ tok,
                             __hip_bfloat16* __restrict__ Ag) {
    const int row = blockIdx.x;
    const float4 v = reinterpret_cast<const float4*>(x + (size_t)tok[row] * ND)[threadIdx.x];
    ushort4 u; u.x = f2bf(v.x); u.y = f2bf(v.y); u.z = f2bf(v.z); u.w = f2bf(v.w);
    reinterpret_cast<ushort4*>(Ag + (size_t)row * ND)[threadIdx.x] = u;
}

// ---------------- grouped GEMM (round-3 structure: 128x128 tile, 4 waves,
// BK=64, 32KB LDS, 4 blocks/CU — inter-block overlap hides latency) ----------
// STAGE 1: h = gelu(Ag @ w1t^T + b1)   N=4096 K=1024, KT=16
// STAGE 2: out += gw*(h @ w2t^T + b2)  N=1024 K=4096 splitK=2, KT=32
//
// Block mapping (the only r4 change that moved counters: FETCH 306->102 MB):
// XCD = bid&7 (HW round-robin). 8 XCDs = 4 tile-groups(18) x {2 N-halves (st1)
// | 2 K-halves (st2)}. Within an XCD, 72-block cells of (9 tiles x 8 nt) keep
// the concurrent working set ~4.3 MB ~ per-XCD L2.

template<int STAGE>
__global__ __launch_bounds__(256, 4) void moe_gemm(
    const __hip_bfloat16* __restrict__ Asrc,   // Ag (st1) or h (st2), contiguous rows
    const __hip_bfloat16* __restrict__ Bt,     // [E][N][K] bf16
    const float* __restrict__ bias,            // [E][N]
    __hip_bfloat16* __restrict__ Hout,
    float* __restrict__ Out,
    const int* __restrict__ offs,
    const int* __restrict__ tok,
    const float* __restrict__ gw,
    const int* __restrict__ tile_e,
    const int* __restrict__ tile_row,
    const int* __restrict__ ntiles)
{
    constexpr int N    = (STAGE == 1) ? NH : ND;
    constexpr int KROW = (STAGE == 1) ? ND : NH;   // row stride of Asrc & Bt
    constexpr int KT   = (STAGE == 1) ? 16 : 32;   // K-tiles of 64 per block

    const int bid = blockIdx.x;
    const int xcd = bid & 7;
    const int c   = bid >> 3;
    int tile, nt, kbase;
    if (STAGE == 1) {                 // c in 0..287: cell = (tile9, nt8) quadrant
        const int cell = c / 72, rr = c % 72;
        tile = (xcd >> 1) * 18 + (cell & 1) * 9 + rr % 9;
        nt   = (xcd & 1) * 16 + (cell >> 1) * 8 + rr / 9;
        kbase = 0;
    } else {                          // c in 0..143
        tile = (xcd >> 1) * 18 + (c / 72) * 9 + (c % 72) % 9;
        nt   = (c % 72) / 9;
        kbase = (xcd & 1) * (NH / 2);
    }
    if (tile >= *ntiles) return;

    const int e = tile_e[tile];
    const int rowbase = tile_row[tile];
    const int end = offs[e + 1];

    __shared__ __align__(16) __hip_bfloat16 sA[128 * 64];
    __shared__ __align__(16) __hip_bfloat16 sB[128 * 64];

    const int tid = threadIdx.x;
    const int w = tid >> 6;
    const int l = tid & 63;

    // --- staging: pre-swizzled per-lane global sources, linear LDS dest ---
    const int srow = tid >> 3;                   // 0..31 (+ i*32)
    const int schunk = (tid & 7) ^ (srow & 7);   // XOR-swizzled source 16B chunk
    const __hip_bfloat16* aptr[4];
    const __hip_bfloat16* bptr[4];
    #pragma unroll
    for (int i = 0; i < 4; ++i) {
        int r = srow + i * 32;
        int re = rowbase + r; if (re > end - 1) re = end - 1;
        aptr[i] = Asrc + (size_t)re * KROW + kbase + schunk * 8;
        bptr[i] = Bt + ((size_t)e * N + (nt * 128 + r)) * KROW + kbase + schunk * 8;
    }
    __hip_bfloat16 *adst[4], *bdst[4];
    #pragma unroll
    for (int i = 0; i < 4; ++i) {
        adst[i] = sA + (i * 256 + w * 64) * 8;   // wave-uniform, linear
        bdst[i] = sB + (i * 256 + w * 64) * 8;
    }

    const int wm = (w >> 1) * 64;
    const int wn = (w & 1) * 64;
    const int l15 = l & 15, l4 = l >> 4;

    f32x4 acc[4][4];
    #pragma unroll
    for (int mi = 0; mi < 4; ++mi)
        #pragma unroll
        for (int ni = 0; ni < 4; ++ni) acc[mi][ni] = (f32x4){0.f, 0.f, 0.f, 0.f};

    // swizzled ds_read byte offsets
    int aoff[4][2], boff[4][2];
    #pragma unroll
    for (int mi = 0; mi < 4; ++mi) {
        int row = wm + mi * 16 + l15;
        #pragma unroll
        for (int ks = 0; ks < 2; ++ks)
            aoff[mi][ks] = row * 128 + (((ks * 4 + l4) ^ (row & 7)) * 16);
    }
    #pragma unroll
    for (int ni = 0; ni < 4; ++ni) {
        int row = wn + ni * 16 + l15;
        #pragma unroll
        for (int ks = 0; ks < 2; ++ks)
            boff[ni][ks] = row * 128 + (((ks * 4 + l4) ^ (row & 7)) * 16);
    }

    const char* sAb = (const char*)sA;
    const char* sBb = (const char*)sB;

    for (int kt = 0; kt < KT; ++kt) {
        #pragma unroll
        for (int i = 0; i < 4; ++i) {
            gload_lds16(aptr[i] + kt * 64, adst[i]);
            gload_lds16(bptr[i] + kt * 64, bdst[i]);
        }
        __syncthreads();
        short8 af[4][2], bfr[4][2];
        #pragma unroll
        for (int mi = 0; mi < 4; ++mi)
            #pragma unroll
            for (int ks = 0; ks < 2; ++ks)
                af[mi][ks] = *(const short8*)(sAb + aoff[mi][ks]);
        #pragma unroll
        for (int ni = 0; ni < 4; ++ni)
            #pragma unroll
            for (int ks = 0; ks < 2; ++ks)
                bfr[ni][ks] = *(const short8*)(sBb + boff[ni][ks]);
        #pragma unroll
        for (int mi = 0; mi < 4; ++mi)
            #pragma unroll
            for (int ni = 0; ni < 4; ++ni)
                #pragma unroll
                for (int ks = 0; ks < 2; ++ks)
                    acc[mi][ni] = __builtin_amdgcn_mfma_f32_16x16x32_bf16(
                        af[mi][ks], bfr[ni][ks], acc[mi][ni], 0, 0, 0);
        __syncthreads();
    }

    // --- epilogue --- C/D layout: col = lane&15, row = (lane>>4)*4 + j  [m89]
    const int ncol0 = nt * 128 + wn;
    #pragma unroll
    for (int mi = 0; mi < 4; ++mi) {
        #pragma unroll
        for (int ni = 0; ni < 4; ++ni) {
            int gn = ncol0 + ni * 16 + l15;
            float bv = bias[e * N + gn];
            #pragma unroll
            for (int j = 0; j < 4; ++j) {
                int re = rowbase + wm + mi * 16 + l4 * 4 + j;
                if (re < end) {
                    float v = acc[mi][ni][j];
                    if (STAGE == 1) {
                        v += bv;
                        Hout[(size_t)re * NH + gn] = __float2bfloat16(fast_gelu(v));
                    } else {
                        if (kbase == 0) v += bv;
                        atomicAdd(&Out[(size_t)tok[re] * ND + gn], gw[re] * v);
                    }
                }
            }
        }
    }
}

// ---------------- launch ----------------

extern "C" void kernel_launch(void* const* d_in, const int* in_sizes, int n_in,
                              void* d_out, int out_size, void* d_ws, size_t ws_size,
                              hipStream_t stream) {
    const float* x   = (const float*)d_in[0];
    const int*   idx = (const int*)d_in[1];
    const float* hw  = (const float*)d_in[2];
    const float* w1  = (const float*)d_in[3];
    const float* b1  = (const float*)d_in[4];
    const float* w2  = (const float*)d_in[5];
    const float* b2  = (const float*)d_in[6];
    float* out = (float*)d_out;

    char* ws = (char*)d_ws;
    size_t off = 0;
    __hip_bfloat16* Ag  = (__hip_bfloat16*)(ws + off); off += (size_t)NROWS * ND * 2;
    __hip_bfloat16* w1t = (__hip_bfloat16*)(ws + off); off += (size_t)NE * ND * NH * 2;
    __hip_bfloat16* w2t = (__hip_bfloat16*)(ws + off); off += (size_t)NE * NH * ND * 2;
    __hip_bfloat16* h   = (__hip_bfloat16*)(ws + off); off += (size_t)NROWS * NH * 2;
    int*   tok     = (int*)(ws + off);   off += NROWS * 4;
    float* gwb     = (float*)(ws + off); off += NROWS * 4;
    int*   cnt     = (int*)(ws + off);   off += 16 * 4;
    int*   offs    = (int*)(ws + off);   off += 16 * 4;
    int*   cursor  = (int*)(ws + off);   off += 16 * 4;
    int*   tile_e  = (int*)(ws + off);   off += MAXT * 4;
    int*   tile_row= (int*)(ws + off);   off += MAXT * 4;
    int*   ntiles  = (int*)(ws + off);   off += 16 * 4;
    (void)ws_size; (void)in_sizes; (void)n_in; (void)out_size;

    hipMemsetAsync(d_out, 0, (size_t)NB * ND * sizeof(float), stream);
    hipMemsetAsync(cnt, 0, 16 * 4, stream);

    k_route_count<<<dim3((NB + 255) / 256), 256, 0, stream>>>(idx, cnt);
    k_route_scan<<<1, 64, 0, stream>>>(cnt, offs, cursor, tile_e, tile_row, ntiles);
    k_route_fill<<<dim3((NB + 255) / 256), 256, 0, stream>>>(idx, hw, cursor, tok, gwb);
    k_gather_cvt<<<dim3(NROWS), 256, 0, stream>>>(x, tok, Ag);

    // LLC-aware interleave: each GEMM consumes the weights converted
    // immediately before it (w1t/w2t still resident in the 256MB LLC).
    k_transpose_cvt<<<dim3(NH / 64, ND / 64, NE), 256, 0, stream>>>(w1, w1t, ND, NH);
    moe_gemm<1><<<dim3(8 * 288), 256, 0, stream>>>(
        Ag, w1t, b1, h, nullptr, offs, tok, gwb, tile_e, tile_row, ntiles);

    k_transpose_cvt<<<dim3(ND / 64, NH / 64, NE), 256, 0, stream>>>(w2, w2t, NH, ND);
    moe_gemm<2><<<dim3(8 * 144), 256, 0, stream>>>(
        h, w2t, b2, nullptr, out, offs, tok, gwb, tile_e, tile_row, ntiles);
}